// Round 2
// baseline (573.410 us; speedup 1.0000x reference)
//
#include <hip/hip_runtime.h>
#include <math.h>

// Coverage attention. B=64, S=2048, H=512.
// e_t[b,s] = v_b + sum_h v_w[h] * tanh( (enc@Wh)[b,s,h] + D[b,h] + cov[b,s]*Wc[h] )
//   D[b,h] = (dec @ Ws)[b,h] + bs[h] + bh[h] + bc[h]
// out = [softmax(e_t) | coverage + softmax(e_t)]
//
// R5: 32 rows/wave (0.5 LDS reads per MFMA -> 41 us LDS floor) AND
// 3 waves/SIMD, with a counted-vmcnt triple-buffer B pipeline:
//  - 256-thr blocks (4 waves x 32 rows), RPB=128, launch_bounds(256,3).
//  - BN=16 per phase, NPH=32; LDS = 3 x 16 KB buffers (48 KB) -> 3 blocks/CU.
//  - B staged via global_load_lds dwordx4, issued 2 phases ahead; phase top is
//    [s_waitcnt vmcnt(4); s_barrier] (raw, counted) -- never drains vmcnt(0),
//    so stages span phases (T3+T4). Params issued before DMA so their implicit
//    waits drain only older stages.
//  - Identity fragment-order LDS layout: ds_read_b128 of contiguous 1KB chunks,
//    conflict-free; transpose_cast pre-lays Bimg in exactly this order.
//  - n-tile/k summation order identical to R3/R4 -> bit-identical outputs.

#define B_ 64
#define S_ 2048
#define H_ 512
#define M_ (B_ * S_)

#define RPB 128          // rows per block (4 waves x 32)
#define BN 16            // n per phase (one 16-col tile)
#define NPH 32           // phases = H_/BN
#define PHS (BN * H_)    // shorts per phase image = 8192
#define PHBYTES (PHS * 2) // 16384 B

typedef __attribute__((ext_vector_type(4))) float f32x4;
typedef __attribute__((ext_vector_type(8))) short s16x8;
typedef unsigned int u32;

__device__ __forceinline__ short f2bf(float f) {
    unsigned u = __float_as_uint(f);
    u += 0x7fffu + ((u >> 16) & 1u);  // RNE
    return (short)(u >> 16);
}

__device__ __forceinline__ s16x8 cvt8(float4 a, float4 b) {
    s16x8 r;
    r[0] = f2bf(a.x); r[1] = f2bf(a.y); r[2] = f2bf(a.z); r[3] = f2bf(a.w);
    r[4] = f2bf(b.x); r[5] = f2bf(b.y); r[6] = f2bf(b.z); r[7] = f2bf(b.w);
    return r;
}

__device__ __forceinline__ float fast_tanh(float x) {
    return 1.0f - 2.0f / (__expf(2.0f * x) + 1.0f);  // saturates correctly
}

// async global->LDS, 16B per lane. LDS dest is wave-uniform; HW adds lane*16.
__device__ __forceinline__ void dma16(const void* g, void* s) {
    __builtin_amdgcn_global_load_lds(
        (const __attribute__((address_space(1))) u32*)g,
        (__attribute__((address_space(3))) u32*)s, 16, 0, 0);
}

// Bimg fragment-order layout (shorts):
//   idx = ph*8192 + kw*512 + q*128 + ml*8 + j
// holds bf16(Wh[k][n]) with n = ph*16 + ml, k = kw*32 + q*8 + j.
__global__ __launch_bounds__(256) void transpose_cast(
    const float* __restrict__ Wh, short* __restrict__ Bimg) {
    __shared__ float tile[32][33];
    const int n0 = blockIdx.x * 32, k0 = blockIdx.y * 32;
    const int tx = threadIdx.x & 31, ty = threadIdx.x >> 5;  // 32 x 8
#pragma unroll
    for (int r = 0; r < 32; r += 8)
        tile[ty + r][tx] = Wh[(size_t)(k0 + ty + r) * H_ + n0 + tx];
    __syncthreads();
    const int kw = k0 >> 5;            // k = k0 + tx
    const int q = tx >> 3, j = tx & 7;
#pragma unroll
    for (int r = 0; r < 32; r += 8) {
        const int n = n0 + ty + r;
        const int ph = n >> 4, mln = n & 15;
        const size_t idx = (size_t)ph * PHS + (size_t)kw * 512
                         + q * 128 + mln * 8 + j;
        Bimg[idx] = f2bf(tile[tx][ty + r]);  // element (k, n)
    }
}

// D[b,h] = dec[b,:] . Ws[:,h] + bs[h] + bh[h] + bc[h]
__global__ __launch_bounds__(256) void dec_kernel(
    const float* __restrict__ dh, const float* __restrict__ Ws,
    const float* __restrict__ bs, const float* __restrict__ bh,
    const float* __restrict__ bc, float* __restrict__ D) {
    const int b = blockIdx.x;
    const int h = blockIdx.y * 256 + threadIdx.x;
    __shared__ float sdh[H_];
    sdh[threadIdx.x] = dh[b * H_ + threadIdx.x];
    sdh[threadIdx.x + 256] = dh[b * H_ + threadIdx.x + 256];
    __syncthreads();
    float acc = bs[h] + bh[h] + bc[h];
#pragma unroll 8
    for (int k = 0; k < H_; ++k)
        acc = fmaf(sdh[k], Ws[k * H_ + h], acc);
    D[b * H_ + h] = acc;
}

__global__ __launch_bounds__(256, 3) void gemm_fused(
    const float* __restrict__ A,      // [M_, H_] fp32 encoder
    const short* __restrict__ Bimg,   // phase-frag image of bf16(Wh^T)
    const float* __restrict__ cover,  // [M_]
    const float* __restrict__ Wc,     // [H_]
    const float* __restrict__ vw,     // [H_]
    const float* __restrict__ D,      // [B_, H_]
    float* __restrict__ e_t) {        // [M_] final logits (minus v_b)
    __shared__ __align__(16) short Bs[3 * PHS];  // 48 KB triple buffer

    const int tid = threadIdx.x;
    const int w = tid >> 6;   // wave 0..3
    const int l = tid & 63;
    const int q = l >> 4;     // k-chunk (A/B) / row-quad (C)
    const int ml = l & 15;    // m (A) / n (B) within 16-tile

    const int row_blk = blockIdx.x * RPB;
    const int b = row_blk >> 11;      // /S_
    const int r0 = row_blk + w * 32;  // this wave's 32 rows

    const int chunk0 = w * 4;         // this wave stages 4 x 1KB chunks/phase

    // ---- prologue: stage phases 0,1 into bufs 0,1 ----
    {
        const char* g0 = (const char*)Bimg + chunk0 * 1024 + l * 16;
        char* s0 = (char*)Bs + chunk0 * 1024;
#pragma unroll
        for (int c = 0; c < 4; ++c) dma16(g0 + c * 1024, s0 + c * 1024);
        const char* g1 = g0 + PHBYTES;
        char* s1 = s0 + PHBYTES;
#pragma unroll
        for (int c = 0; c < 4; ++c) dma16(g1 + c * 1024, s1 + c * 1024);
    }

    // ---- A fill: 2 m-tiles x 16 k-windows, fp32->bf16 once ----
    s16x8 a[2][16];
    {
        const float* ap = A + (size_t)(r0 + ml) * H_ + q * 8;
#pragma unroll
        for (int kw = 0; kw < 16; ++kw) {
#pragma unroll
            for (int t = 0; t < 2; ++t) {
                const float* p = ap + (size_t)t * 16 * H_ + kw * 32;
                float4 x = *(const float4*)p;
                float4 y = *(const float4*)(p + 4);
                a[t][kw] = cvt8(x, y);
            }
        }
    }

    // coverage per C-row (C layout: col=ml, row=q*4+reg)
    float cv[2][4];
#pragma unroll
    for (int t = 0; t < 2; ++t)
#pragma unroll
        for (int r = 0; r < 4; ++r)
            cv[t][r] = cover[r0 + t * 16 + q * 4 + r];

    float ecur[2][4] = {};

    int cur = 0;  // buffer of current phase (p % 3)
    const char* gdma = (const char*)Bimg + 2 * (size_t)PHBYTES
                     + chunk0 * 1024 + l * 16;

    for (int p = 0; p < NPH; ++p) {
        // counted wait: own 2-phase-old stage done; barrier certifies all waves
        asm volatile("s_waitcnt vmcnt(4)" ::: "memory");
        __builtin_amdgcn_sched_barrier(0);
        __builtin_amdgcn_s_barrier();

        // per-phase column params FIRST (so their implicit waits drain only
        // stages older than the one issued below)
        const int n0 = p * BN + ml;
        const float wc = Wc[n0];
        const float vv = vw[n0];
        const float dd = D[b * H_ + n0];
        __builtin_amdgcn_sched_barrier(0);  // pin params before the DMA issue

        // stage phase p+2 into buffer (cur+2)%3 (fire-and-forget)
        if (p + 2 < NPH) {
            const int nb = (cur == 0) ? 2 : cur - 1;  // (cur+2)%3
            char* sd = (char*)Bs + nb * PHBYTES + chunk0 * 1024;
#pragma unroll
            for (int c = 0; c < 4; ++c) dma16(gdma + c * 1024, sd + c * 1024);
            gdma += PHBYTES;
        }

        const short* bp = Bs + cur * PHS;
        f32x4 acc0 = (f32x4)0.0f, acc1 = (f32x4)0.0f;
#pragma unroll
        for (int kw = 0; kw < 16; ++kw) {
            s16x8 bfr = *(const s16x8*)(bp + kw * 512 + l * 8);
            acc0 = __builtin_amdgcn_mfma_f32_16x16x32_bf16(a[0][kw], bfr, acc0, 0, 0, 0);
            acc1 = __builtin_amdgcn_mfma_f32_16x16x32_bf16(a[1][kw], bfr, acc1, 0, 0, 0);
        }

        // e partials: x = acc + cov*Wc + D; e += vw*tanh(x)
        // (n ascending by 16-tile, same order as R3/R4)
#pragma unroll
        for (int r = 0; r < 4; ++r) {
            ecur[0][r] += vv * fast_tanh(acc0[r] + fmaf(cv[0][r], wc, dd));
            ecur[1][r] += vv * fast_tanh(acc1[r] + fmaf(cv[1][r], wc, dd));
        }

        cur = (cur == 2) ? 0 : cur + 1;
    }

    // final cross-lane (ml) reduction and store
#pragma unroll
    for (int t = 0; t < 2; ++t) {
        float p0 = ecur[t][0], p1 = ecur[t][1], p2 = ecur[t][2], p3 = ecur[t][3];
#pragma unroll
        for (int s = 1; s < 16; s <<= 1) {
            p0 += __shfl_xor(p0, s, 64);
            p1 += __shfl_xor(p1, s, 64);
            p2 += __shfl_xor(p2, s, 64);
            p3 += __shfl_xor(p3, s, 64);
        }
        if (ml == 0) {
            float4 st = {p0, p1, p2, p3};
            *(float4*)&e_t[r0 + t * 16 + q * 4] = st;
        }
    }
}

__global__ __launch_bounds__(256) void softmax_kernel(
    const float* __restrict__ e_t, const float* __restrict__ cover,
    const float* __restrict__ vb, float* __restrict__ out) {
    const int b = blockIdx.x;
    const int tid = threadIdx.x;
    const float vbv = vb[0];

    float e[8];
    float mx = -1e30f;
#pragma unroll
    for (int r = 0; r < 8; ++r) {
        e[r] = e_t[b * S_ + r * 256 + tid] + vbv;
        mx = fmaxf(mx, e[r]);
    }
#pragma unroll
    for (int off = 32; off >= 1; off >>= 1) mx = fmaxf(mx, __shfl_xor(mx, off, 64));

    __shared__ float sm[4], ss[4], sbc[2];
    const int wid = tid >> 6, lane = tid & 63;
    if (lane == 0) sm[wid] = mx;
    __syncthreads();
    if (tid == 0) sbc[0] = fmaxf(fmaxf(sm[0], sm[1]), fmaxf(sm[2], sm[3]));
    __syncthreads();
    mx = sbc[0];

    float ex[8];
    float sum = 0.0f;
#pragma unroll
    for (int r = 0; r < 8; ++r) {
        ex[r] = __expf(e[r] - mx);
        sum += ex[r];
    }
#pragma unroll
    for (int off = 32; off >= 1; off >>= 1) sum += __shfl_xor(sum, off, 64);
    if (lane == 0) ss[wid] = sum;
    __syncthreads();
    if (tid == 0) sbc[1] = ss[0] + ss[1] + ss[2] + ss[3];
    __syncthreads();
    const float inv = 1.0f / sbc[1];

#pragma unroll
    for (int r = 0; r < 8; ++r) {
        const int s = r * 256 + tid;
        const float a = ex[r] * inv;
        out[b * S_ + s] = a;                           // a_t
        out[M_ + b * S_ + s] = cover[b * S_ + s] + a;  // sum_coverage
    }
}

extern "C" void kernel_launch(void* const* d_in, const int* in_sizes, int n_in,
                              void* d_out, int out_size, void* d_ws, size_t ws_size,
                              hipStream_t stream) {
    const float* enc = (const float*)d_in[0];
    const float* dh  = (const float*)d_in[1];
    const float* cov = (const float*)d_in[2];
    const float* Wh  = (const float*)d_in[3];
    const float* bh  = (const float*)d_in[4];
    const float* Ws  = (const float*)d_in[5];
    const float* bs  = (const float*)d_in[6];
    const float* Wc  = (const float*)d_in[7];
    const float* bc  = (const float*)d_in[8];
    const float* vw  = (const float*)d_in[9];
    const float* vb  = (const float*)d_in[10];
    float* out = (float*)d_out;

    float* e_t  = (float*)d_ws;              // M_ floats
    float* Dws  = e_t + M_;                  // B_*H_ floats
    short* Whbt = (short*)(Dws + B_ * H_);   // H_*H_ bf16 (phase-frag image)

    transpose_cast<<<dim3(H_ / 32, H_ / 32), 256, 0, stream>>>(Wh, Whbt);
    dec_kernel<<<dim3(B_, 2), 256, 0, stream>>>(dh, Ws, bs, bh, bc, Dws);
    gemm_fused<<<M_ / RPB, 256, 0, stream>>>(enc, Whbt, cov, Wc, vw, Dws, e_t);
    softmax_kernel<<<B_, 256, 0, stream>>>(e_t, cov, vb, out);
}

// Round 3
// 500.210 us; speedup vs baseline: 1.1463x; 1.1463x over previous
//
#include <hip/hip_runtime.h>
#include <math.h>

// Coverage attention. B=64, S=2048, H=512.
// e_t[b,s] = v_b + sum_h v_w[h] * tanh( (enc@Wh)[b,s,h] + D[b,h] + cov[b,s]*Wc[h] )
//   D[b,h] = (dec @ Ws)[b,h] + bs[h] + bh[h] + bc[h]
// out = [softmax(e_t) | coverage + softmax(e_t)]
//
// R6: barrier-free L2-direct streaming design.
//  - Each wave owns 32 rows for its lifetime: A (fp32) loaded+converted to
//    bf16 MFMA fragments ONCE (128 VGPR), then streams ALL 32 n-tiles of B
//    DIRECTLY from global memory (Wh bf16 image = 512 KB, L2-resident per
//    XCD) -- no LDS, no __syncthreads, no staging. Waves fully independent:
//    one wave's HBM A-fill overlaps its SIMD-partner's MFMA burst.
//  - B-fragment reads are 1 KB coalesced global_load_dwordx4 (lane l reads
//    16B at frag_base + l*16), rotated through an 8-deep register buffer
//    (prefetch distance 8 frags = 16 MFMAs ~ 400+ cyc > L2 latency).
//  - launch_bounds(256,2): ~200 regs, NO spill (R4/R5 lesson: the (256,3)/
//    (512,4) caps spilled A-frags to scratch -> WRITE_SIZE 105-127 MB).
//  - n-tile / k accumulation order identical to R3 -> bit-identical e_t.

#define B_ 64
#define S_ 2048
#define H_ 512
#define M_ (B_ * S_)

#define NT 32            // n-tiles (16 cols each)
#define NFRAG 512        // total B frags = NT * 16 kw
#define FRAG_SHORTS 512  // shorts per frag (1 KB)

typedef __attribute__((ext_vector_type(4))) float f32x4;
typedef __attribute__((ext_vector_type(8))) short s16x8;

__device__ __forceinline__ short f2bf(float f) {
    unsigned u = __float_as_uint(f);
    u += 0x7fffu + ((u >> 16) & 1u);  // RNE
    return (short)(u >> 16);
}

__device__ __forceinline__ s16x8 cvt8(float4 a, float4 b) {
    s16x8 r;
    r[0] = f2bf(a.x); r[1] = f2bf(a.y); r[2] = f2bf(a.z); r[3] = f2bf(a.w);
    r[4] = f2bf(b.x); r[5] = f2bf(b.y); r[6] = f2bf(b.z); r[7] = f2bf(b.w);
    return r;
}

__device__ __forceinline__ float fast_tanh(float x) {
    return 1.0f - 2.0f / (__expf(2.0f * x) + 1.0f);  // saturates correctly
}

// Bimg fragment-order layout (shorts):
//   idx = nt*8192 + kw*512 + q*128 + ml*8 + j
// holds bf16(Wh[k][n]) with n = nt*16 + ml, k = kw*32 + q*8 + j.
// Frag (nt,kw) is a contiguous 1 KB block; lane l=(q*16+ml) reads its 16 B
// at offset l*16 -> perfectly coalesced dwordx4.
__global__ __launch_bounds__(256) void transpose_cast(
    const float* __restrict__ Wh, short* __restrict__ Bimg) {
    __shared__ float tile[32][33];
    const int n0 = blockIdx.x * 32, k0 = blockIdx.y * 32;
    const int tx = threadIdx.x & 31, ty = threadIdx.x >> 5;  // 32 x 8
#pragma unroll
    for (int r = 0; r < 32; r += 8)
        tile[ty + r][tx] = Wh[(size_t)(k0 + ty + r) * H_ + n0 + tx];
    __syncthreads();
    const int kw = k0 >> 5;            // k = k0 + tx
    const int q = tx >> 3, j = tx & 7;
#pragma unroll
    for (int r = 0; r < 32; r += 8) {
        const int n = n0 + ty + r;
        const int nt = n >> 4, mln = n & 15;
        const size_t idx = (size_t)nt * 8192 + (size_t)kw * FRAG_SHORTS
                         + q * 128 + mln * 8 + j;
        Bimg[idx] = f2bf(tile[tx][ty + r]);  // element (k, n)
    }
}

// D[b,h] = dec[b,:] . Ws[:,h] + bs[h] + bh[h] + bc[h]
__global__ __launch_bounds__(256) void dec_kernel(
    const float* __restrict__ dh, const float* __restrict__ Ws,
    const float* __restrict__ bs, const float* __restrict__ bh,
    const float* __restrict__ bc, float* __restrict__ D) {
    const int b = blockIdx.x;
    const int h = blockIdx.y * 256 + threadIdx.x;
    __shared__ float sdh[H_];
    sdh[threadIdx.x] = dh[b * H_ + threadIdx.x];
    sdh[threadIdx.x + 256] = dh[b * H_ + threadIdx.x + 256];
    __syncthreads();
    float acc = bs[h] + bh[h] + bc[h];
#pragma unroll 8
    for (int k = 0; k < H_; ++k)
        acc = fmaf(sdh[k], Ws[k * H_ + h], acc);
    D[b * H_ + h] = acc;
}

__global__ __launch_bounds__(256, 2) void gemm_fused(
    const float* __restrict__ A,      // [M_, H_] fp32 encoder
    const short* __restrict__ Bimg,   // frag-order image of bf16(Wh^T)
    const float* __restrict__ cover,  // [M_]
    const float* __restrict__ Wc,     // [H_]
    const float* __restrict__ vw,     // [H_]
    const float* __restrict__ D,      // [B_, H_]
    float* __restrict__ e_t) {        // [M_] final logits (minus v_b)
    const int tid = threadIdx.x;
    const int w = tid >> 6;   // wave 0..3
    const int l = tid & 63;
    const int q = l >> 4;     // k-chunk (A/B) / row-quad (C)
    const int ml = l & 15;    // m (A) / n (B) within 16-tile
    const int l8 = l * 8;     // shorts offset of this lane within a frag

    const int wave_id = blockIdx.x * 4 + w;  // 0..4095
    const int r0 = wave_id * 32;             // this wave's 32 rows (lifetime)
    const int b = r0 >> 11;                  // /S_

    // ---- B prologue: preload frags 0..7 into the rotation buffer ----
    // (issued first so their L2 latency hides under the A-fill below)
    s16x8 bf[8];
#pragma unroll
    for (int f = 0; f < 8; ++f)
        bf[f] = *(const s16x8*)(Bimg + (size_t)f * FRAG_SHORTS + l8);

    // ---- A fill: 2 m-tiles x 16 k-windows, fp32->bf16 once ----
    s16x8 a[2][16];
    {
        const float* ap = A + (size_t)(r0 + ml) * H_ + q * 8;
#pragma unroll
        for (int kw = 0; kw < 16; ++kw) {
#pragma unroll
            for (int t = 0; t < 2; ++t) {
                const float* p = ap + (size_t)t * 16 * H_ + kw * 32;
                float4 x = *(const float4*)p;
                float4 y = *(const float4*)(p + 4);
                a[t][kw] = cvt8(x, y);
            }
        }
    }

    // coverage per C-row (C layout: col=ml, row=q*4+reg)
    float cv[2][4];
#pragma unroll
    for (int t = 0; t < 2; ++t)
#pragma unroll
        for (int r = 0; r < 4; ++r)
            cv[t][r] = cover[r0 + t * 16 + q * 4 + r];

    float ecur[2][4] = {};

    // ---- main loop: 32 n-tiles, B streamed from L2, 8-deep rotation ----
#pragma unroll 1
    for (int nt = 0; nt < NT; ++nt) {
        // per-tile column params: issued at tile top, consumed after the
        // 32-MFMA burst -> latency fully hidden
        const int n0 = nt * 16 + ml;
        const float wcv = Wc[n0];
        const float vvv = vw[n0];
        const float ddv = D[b * H_ + n0];

        f32x4 acc0 = (f32x4)0.0f, acc1 = (f32x4)0.0f;
#pragma unroll
        for (int kw = 0; kw < 16; ++kw) {
            const s16x8 cur = bf[kw & 7];  // frag f = nt*16+kw
            // prefetch frag f+8 into the same slot (clamped tail reload is
            // dead data, never consumed -- branchless, scalar-uniform addr)
            int fn = nt * 16 + kw + 8;
            if (fn > NFRAG - 1) fn = NFRAG - 1;
            bf[kw & 7] = *(const s16x8*)(Bimg + (size_t)fn * FRAG_SHORTS + l8);
            acc0 = __builtin_amdgcn_mfma_f32_16x16x32_bf16(a[0][kw], cur, acc0, 0, 0, 0);
            acc1 = __builtin_amdgcn_mfma_f32_16x16x32_bf16(a[1][kw], cur, acc1, 0, 0, 0);
        }

        // e partials: x = acc + cov*Wc + D; e += vw*tanh(x)
        // (n ascending by 16-tile, same order as R3)
#pragma unroll
        for (int r = 0; r < 4; ++r) {
            ecur[0][r] += vvv * fast_tanh(acc0[r] + fmaf(cv[0][r], wcv, ddv));
            ecur[1][r] += vvv * fast_tanh(acc1[r] + fmaf(cv[1][r], wcv, ddv));
        }
    }

    // final cross-lane (ml) reduction and store
#pragma unroll
    for (int t = 0; t < 2; ++t) {
        float p0 = ecur[t][0], p1 = ecur[t][1], p2 = ecur[t][2], p3 = ecur[t][3];
#pragma unroll
        for (int s = 1; s < 16; s <<= 1) {
            p0 += __shfl_xor(p0, s, 64);
            p1 += __shfl_xor(p1, s, 64);
            p2 += __shfl_xor(p2, s, 64);
            p3 += __shfl_xor(p3, s, 64);
        }
        if (ml == 0) {
            float4 st = {p0, p1, p2, p3};
            *(float4*)&e_t[r0 + t * 16 + q * 4] = st;
        }
    }
}

__global__ __launch_bounds__(256) void softmax_kernel(
    const float* __restrict__ e_t, const float* __restrict__ cover,
    const float* __restrict__ vb, float* __restrict__ out) {
    const int b = blockIdx.x;
    const int tid = threadIdx.x;
    const float vbv = vb[0];

    float e[8];
    float mx = -1e30f;
#pragma unroll
    for (int r = 0; r < 8; ++r) {
        e[r] = e_t[b * S_ + r * 256 + tid] + vbv;
        mx = fmaxf(mx, e[r]);
    }
#pragma unroll
    for (int off = 32; off >= 1; off >>= 1) mx = fmaxf(mx, __shfl_xor(mx, off, 64));

    __shared__ float sm[4], ss[4], sbc[2];
    const int wid = tid >> 6, lane = tid & 63;
    if (lane == 0) sm[wid] = mx;
    __syncthreads();
    if (tid == 0) sbc[0] = fmaxf(fmaxf(sm[0], sm[1]), fmaxf(sm[2], sm[3]));
    __syncthreads();
    mx = sbc[0];

    float ex[8];
    float sum = 0.0f;
#pragma unroll
    for (int r = 0; r < 8; ++r) {
        ex[r] = __expf(e[r] - mx);
        sum += ex[r];
    }
#pragma unroll
    for (int off = 32; off >= 1; off >>= 1) sum += __shfl_xor(sum, off, 64);
    if (lane == 0) ss[wid] = sum;
    __syncthreads();
    if (tid == 0) sbc[1] = ss[0] + ss[1] + ss[2] + ss[3];
    __syncthreads();
    const float inv = 1.0f / sbc[1];

#pragma unroll
    for (int r = 0; r < 8; ++r) {
        const int s = r * 256 + tid;
        const float a = ex[r] * inv;
        out[b * S_ + s] = a;                           // a_t
        out[M_ + b * S_ + s] = cover[b * S_ + s] + a;  // sum_coverage
    }
}

extern "C" void kernel_launch(void* const* d_in, const int* in_sizes, int n_in,
                              void* d_out, int out_size, void* d_ws, size_t ws_size,
                              hipStream_t stream) {
    const float* enc = (const float*)d_in[0];
    const float* dh  = (const float*)d_in[1];
    const float* cov = (const float*)d_in[2];
    const float* Wh  = (const float*)d_in[3];
    const float* bh  = (const float*)d_in[4];
    const float* Ws  = (const float*)d_in[5];
    const float* bs  = (const float*)d_in[6];
    const float* Wc  = (const float*)d_in[7];
    const float* bc  = (const float*)d_in[8];
    const float* vw  = (const float*)d_in[9];
    const float* vb  = (const float*)d_in[10];
    float* out = (float*)d_out;

    float* e_t  = (float*)d_ws;              // M_ floats
    float* Dws  = e_t + M_;                  // B_*H_ floats
    short* Whbt = (short*)(Dws + B_ * H_);   // H_*H_ bf16 (frag image)

    transpose_cast<<<dim3(H_ / 32, H_ / 32), 256, 0, stream>>>(Wh, Whbt);
    dec_kernel<<<dim3(B_, 2), 256, 0, stream>>>(dh, Ws, bs, bh, bc, Dws);
    gemm_fused<<<M_ / 128, 256, 0, stream>>>(enc, Whbt, cov, Wc, vw, Dws, e_t);
    softmax_kernel<<<B_, 256, 0, stream>>>(e_t, cov, vb, out);
}